// Round 14
// baseline (5865.073 us; speedup 1.0000x reference)
//
#include <hip/hip_runtime.h>

#define S_LEN 16384
#define BATCH 128
#define HID   128
#define NTHR  256
#define CHUNK 256
#define NCHUNK (S_LEN / CHUNK)

typedef float f2 __attribute__((ext_vector_type(2)));

// Clamp-free tanh: tanh(z) = 1 - 2/(e^{2z}+1).
__device__ __forceinline__ float fast_tanh(float z) {
    float e = __builtin_amdgcn_exp2f(z * 2.8853900817779268f);
    return fmaf(-2.0f, __builtin_amdgcn_rcpf(e + 1.0f), 1.0f);
}

// Compiler-generated lane broadcast (hazard handling by LLVM).
__device__ __forceinline__ float rdlane(float v, int lane) {
    return __uint_as_float(__builtin_amdgcn_readlane(__float_as_uint(v), lane));
}

// One block = one chain: 256 threads = 4 waves, 1 wave/SIMD.
// K split ACROSS waves (wave w owns rows [32w,32w+32)); lane l owns units
// jA=l, jB=l+64; weights row-packed {W2[i][jA],W2[i][jB]} as 32 f2 =
// 64 arch VGPRs (resident: VGPR_Count=132, R10-R13). h1 broadcast via
// readlane (VALU pipe); single barrier per step for the pv exchange.
// ROUND-14 (latency-window rebalance):
//  (a) all off-path work (x select, axn, pre, y update, ycap) moved to the
//      POST-barrier region to fill the ~130-cyc pv ds_read latency window
//      (compiler can't move code across __syncthreads; placement binds).
//      pv reads issue first; the lds_x read follows (DS in-order return ->
//      q-sum only waits lgkmcnt(1), xn stays in flight).
//  (b) b3s folded into carried 'pre': h1 arg = fmaf(c1, sv, pre), deleting
//      the serial svb=sv+b3s add at the readlane->tanh1 hinge.
//  (c) unroll 2: parity buffer addressing becomes static.
__attribute__((amdgpu_waves_per_eu(1, 1)))
__global__ __launch_bounds__(NTHR, 1) void ode_scan_kernel(
    const float* __restrict__ x,
    const float* __restrict__ W1, const float* __restrict__ b1,
    const float* __restrict__ W2, const float* __restrict__ b2,
    const float* __restrict__ W3, const float* __restrict__ b3,
    float* __restrict__ out)
{
    const int tid  = threadIdx.x;
    const int bb   = blockIdx.x;     // batch chain index
    const int l    = tid & 63;       // lane
    const int w    = tid >> 6;       // wave = K-quarter
    const int koff = w << 5;         // first K-row of this wave
    const int jA   = l;              // owned units
    const int jB   = l + 64;
    const int row  = koff + (l & 31);// layer-1 row (lanes 32.. duplicate)

    __shared__ __align__(16) f2    lds_p[2][4][64]; // [par][wave][lane]={pA,pB}
    __shared__ float lds_x[2][CHUNK];

    // layer-1 constants for this lane's K-row
    const float c1  = W1[row];          // y coefficient (row 0 of W1)
    const float w1x = W1[HID + row];    // x coefficient (row 1 of W1)
    const float b1r = b1[row];
    // layer-2/3 constants for the two owned units
    const float b2A = b2[jA], b2B = b2[jB];
    const float w3A = W3[jA], w3B = W3[jB];
    const float b3s = b3[0];

    // 32 rows x {unitA, unitB}: w##r##_##t = {W2[koff+4r+t][jA], ..[jB]}.
#define REP8(M) M(0) M(1) M(2) M(3) M(4) M(5) M(6) M(7)
#define DECLW(r) \
    f2 w##r##_0 = { W2[(koff+4*(r)+0)*HID + jA], W2[(koff+4*(r)+0)*HID + jB] }; \
    f2 w##r##_1 = { W2[(koff+4*(r)+1)*HID + jA], W2[(koff+4*(r)+1)*HID + jB] }; \
    f2 w##r##_2 = { W2[(koff+4*(r)+2)*HID + jA], W2[(koff+4*(r)+2)*HID + jB] }; \
    f2 w##r##_3 = { W2[(koff+4*(r)+3)*HID + jA], W2[(koff+4*(r)+3)*HID + jB] };
    REP8(DECLW)

    // Preload x chunk 0: lds_x[0][t] = x[t][bb].
    lds_x[0][tid] = x[tid * BATCH + bb];
    __syncthreads();

    // Carried state: y = y_n, sv = last step's raw DPP sum (pre-b3), pre =
    // c1*(y_n + b3s) + ax_{n}, so h1 arg = fmaf(c1, sv, pre).
    float y    = 0.0f;
    float ycap = 0.0f;
    float sv   = 0.0f;
    float pre  = fmaf(w1x, lds_x[0][0], b1r);  // = ax_0 (y_0 = 0, sv = 0)
    int   cur  = 0;

    for (int c = 0; c < NCHUNK; ++c) {
        // Refill other x buffer with next chunk (dup-load last, unused).
        int nb = (c + 1 < NCHUNK) ? (c + 1) : c;
        float xf = x[(nb * CHUNK + tid) * BATCH + bb];
        lds_x[cur ^ 1][tid] = xf;

#pragma unroll 2
        for (int s = 0; s < CHUNK; ++s) {
            // ---- layer 1: z = c1*y_n + ax_n = pre + c1*sv_{n-1} ----
            float h1 = fast_tanh(fmaf(c1, sv, pre));

            // ---- layer 2 (quarter-K x 2 units): readlane broadcast +
            //      one pk-FMA per row covering both units ----
            f2 a0 = {0.f,0.f}, a1 = {0.f,0.f}, a2 = {0.f,0.f}, a3 = {0.f,0.f};
#define MACR(r) { \
            float h0_ = rdlane(h1, 4*(r)+0); f2 s0_ = { h0_, h0_ }; \
            a0 = __builtin_elementwise_fma(s0_, w##r##_0, a0); \
            float h1_ = rdlane(h1, 4*(r)+1); f2 s1_ = { h1_, h1_ }; \
            a1 = __builtin_elementwise_fma(s1_, w##r##_1, a1); \
            float h2_ = rdlane(h1, 4*(r)+2); f2 s2_ = { h2_, h2_ }; \
            a2 = __builtin_elementwise_fma(s2_, w##r##_2, a2); \
            float h3_ = rdlane(h1, 4*(r)+3); f2 s3_ = { h3_, h3_ }; \
            a3 = __builtin_elementwise_fma(s3_, w##r##_3, a3); }
            REP8(MACR)

            f2 pv = (a0 + a1) + (a2 + a3);   // {pA, pB} for this K-quarter

            const int buf = s & 1;           // static under unroll 2
            lds_p[buf][w][l] = pv;           // ds_write_b64

            __syncthreads();                 // the ONE barrier per step

            // ---- post-barrier: pv reads first (critical), then off-path
            //      work fills the ds_read latency window ----
            f2 r0 = lds_p[buf][0][l];
            f2 r1 = lds_p[buf][1][l];
            f2 r2 = lds_p[buf][2][l];
            f2 r3 = lds_p[buf][3][l];

            float xn  = (s < CHUNK - 1) ? lds_x[cur][s + 1] : lds_x[cur ^ 1][0];
            float yb  = y + b3s;             // y_n + b3 (off-path)
            float axn = fmaf(w1x, xn, b1r);  // ax_{n+1} (off-path)
            pre = fmaf(c1, yb, axn);         // c1*(y_n+b3s) + ax_{n+1}

            f2 q  = (r0 + r1) + (r2 + r3);   // {sum_jA, sum_jB} over K=128
            float h2A = fast_tanh(q.x + b2A);
            float h2B = fast_tanh(q.y + b2B);
            float p   = fmaf(h2A, w3A, h2B * w3B);

            // 64-lane DPP sum (covers all 128 units) -> lane 63
            asm volatile(
                "s_nop 1\n\t"
                "v_add_f32 %0, %0, %0 row_shr:1 bound_ctrl:0\n\t"
                "s_nop 1\n\t"
                "v_add_f32 %0, %0, %0 row_shr:2 bound_ctrl:0\n\t"
                "s_nop 1\n\t"
                "v_add_f32 %0, %0, %0 row_shr:4 bank_mask:0xe\n\t"
                "s_nop 1\n\t"
                "v_add_f32 %0, %0, %0 row_shr:8 bank_mask:0xc\n\t"
                "s_nop 1\n\t"
                "v_add_f32 %0, %0, %0 row_bcast:15 row_mask:0xa\n\t"
                "s_nop 1\n\t"
                "v_add_f32 %0, %0, %0 row_bcast:31 row_mask:0xc\n\t"
                : "+v"(p));
            sv = rdlane(p, 63);              // raw Δ (pre-b3); feeds next h1

            y = yb + sv;                     // y_{n+1} (off-path)
            ycap = (tid == s) ? y : ycap;    // thread s captures ys[c*256+s]
        }
        out[(c * CHUNK + tid) * BATCH + bb] = ycap;   // 256 steps per store
        cur ^= 1;
    }
}

extern "C" void kernel_launch(void* const* d_in, const int* in_sizes, int n_in,
                              void* d_out, int out_size, void* d_ws, size_t ws_size,
                              hipStream_t stream) {
    const float* x  = (const float*)d_in[0];
    const float* W1 = (const float*)d_in[1];
    const float* b1 = (const float*)d_in[2];
    const float* W2 = (const float*)d_in[3];
    const float* b2 = (const float*)d_in[4];
    const float* W3 = (const float*)d_in[5];
    const float* b3 = (const float*)d_in[6];
    float* out = (float*)d_out;

    hipLaunchKernelGGL(ode_scan_kernel, dim3(BATCH), dim3(NTHR), 0, stream,
                       x, W1, b1, W2, b2, W3, b3, out);
}